// Round 3
// baseline (191.734 us; speedup 1.0000x reference)
//
#include <hip/hip_runtime.h>

#define N 8192
#define D 256
#define BM 128                    // I-tile rows
#define BJ 64                     // J-tile rows
#define JG 8                      // J-tiles per block
#define GJ (N / BJ / JG)          // 16
#define GI (N / BM)               // 64
#define NPART (3 * GI * GJ)       // 3072 partials

typedef int   i32x4 __attribute__((ext_vector_type(4)));
typedef int   i32x8 __attribute__((ext_vector_type(8)));
typedef float f32x4 __attribute__((ext_vector_type(4)));
typedef float f32x2 __attribute__((ext_vector_type(2)));

// -------- prep: fp32 -> fp8 e4m3 (packed), norms of the DEQUANTIZED values ----
__device__ __forceinline__ unsigned pack_fp8x4(float a, float b, float c, float d) {
    unsigned lo = __builtin_amdgcn_cvt_pk_fp8_f32(a, b, 0, false);
    return __builtin_amdgcn_cvt_pk_fp8_f32(c, d, lo, true);
}
__device__ __forceinline__ float dequant_sumsq(unsigned q) {
    const float v0 = __builtin_amdgcn_cvt_f32_fp8(q, 0);
    const float v1 = __builtin_amdgcn_cvt_f32_fp8(q, 1);
    const float v2 = __builtin_amdgcn_cvt_f32_fp8(q, 2);
    const float v3 = __builtin_amdgcn_cvt_f32_fp8(q, 3);
    return fmaf(v0, v0, fmaf(v1, v1, fmaf(v2, v2, v3 * v3)));
}

__global__ void prep_kernel(const float* __restrict__ x1, const float* __restrict__ x2,
                            unsigned* __restrict__ x1q, unsigned* __restrict__ x2q,
                            unsigned* __restrict__ pq,
                            float* __restrict__ sq1, float* __restrict__ sq2,
                            float* __restrict__ sqp) {
    const int tid = threadIdx.x, lane = tid & 63, wv = tid >> 6;
    const int row = blockIdx.x * 4 + wv;
    const size_t eb = (size_t)row * D + lane * 4;
    const float4 a = *(const float4*)(x1 + eb);
    const float4 b = *(const float4*)(x2 + eb);
    const float px = 0.5f * (a.x + b.x), py = 0.5f * (a.y + b.y);
    const float pz = 0.5f * (a.z + b.z), pw = 0.5f * (a.w + b.w);
    const unsigned qa = pack_fp8x4(a.x, a.y, a.z, a.w);
    const unsigned qb = pack_fp8x4(b.x, b.y, b.z, b.w);
    const unsigned qp = pack_fp8x4(px, py, pz, pw);
    const size_t wb = (size_t)row * (D / 4) + lane;
    x1q[wb] = qa; x2q[wb] = qb; pq[wb] = qp;
    float s1 = dequant_sumsq(qa), s2 = dequant_sumsq(qb), sp = dequant_sumsq(qp);
    #pragma unroll
    for (int o = 32; o > 0; o >>= 1) {
        s1 += __shfl_down(s1, o, 64);
        s2 += __shfl_down(s2, o, 64);
        sp += __shfl_down(sp, o, 64);
    }
    if (lane == 0) { sq1[row] = s1; sq2[row] = s2; sqp[row] = sp; }
}

// -------- main ---------------------------------------------------------------
__device__ __forceinline__ f32x4 mfma8(i32x8 a, i32x8 b, f32x4 c) {
    return __builtin_amdgcn_mfma_scale_f32_16x16x128_f8f6f4(
        a, b, c, 0, 0, 0, 0x7F7F7F7F, 0, 0x7F7F7F7F);
}

// B-fragment from LDS: 32 fp8 (k-chunk quad*32) of row m; 16B blocks XOR-swizzled by row&7
__device__ __forceinline__ i32x8 read_frag(const unsigned char* Ts, int m, int quad) {
    const int r7 = m & 7;
    const i32x4 lo = *(const i32x4*)(Ts + m * 128 + ((((2 * quad)     ^ r7)) << 4));
    const i32x4 hi = *(const i32x4*)(Ts + m * 128 + ((((2 * quad + 1) ^ r7)) << 4));
    i32x8 f;
    f[0] = lo[0]; f[1] = lo[1]; f[2] = lo[2]; f[3] = lo[3];
    f[4] = hi[0]; f[5] = hi[1]; f[6] = hi[2]; f[7] = hi[3];
    return f;
}

// stage a 64-row x 128B K-chunk (8 KB, 8 groups); 2 global_load_lds per wave
__device__ __forceinline__ void stageB(const unsigned char* __restrict__ g,
                                       unsigned char* s, int rowbase, size_t kb,
                                       int wv, int srow, int sblk) {
    #pragma unroll
    for (int it = 0; it < 2; ++it) {
        const int grp = wv * 2 + it;
        const int row = grp * 8 + srow;
        __builtin_amdgcn_global_load_lds(
            (const __attribute__((address_space(1))) void*)(g + (size_t)(rowbase + row) * D + kb + sblk * 16),
            (__attribute__((address_space(3))) void*)(s + grp * 1024), 16, 0, 0);
    }
}

// packed-f32 log2-sum over 32 entries (4 ti x 2 tj x 4 regs); caller applies ln2
__device__ __forceinline__ float logsumP(const f32x4 (&acc)[4][2],
                                         const f32x2 (&sa01)[4], const f32x2 (&sa23)[4],
                                         const float sb[2]) {
    float s = 0.0f;
    #pragma unroll
    for (int ti = 0; ti < 4; ++ti) {
        f32x2 pr = {1.0f, 1.0f};
        #pragma unroll
        for (int tj = 0; tj < 2; ++tj) {
            const f32x2 sbv = {sb[tj], sb[tj]};
            const f32x2 t01 = sa01[ti] + sbv, t23 = sa23[ti] + sbv;
            const f32x2 v01 = {acc[ti][tj][0], acc[ti][tj][1]};
            const f32x2 v23 = {acc[ti][tj][2], acc[ti][tj][3]};
            f32x2 d01 = t01 - 2.0f * v01;
            f32x2 d23 = t23 - 2.0f * v23;
            d01 = __builtin_elementwise_max(d01, (f32x2){1.0f, 1.0f});
            d23 = __builtin_elementwise_max(d23, (f32x2){1.0f, 1.0f});
            pr *= d01; pr *= d23;
        }
        s += __log2f(pr.x * pr.y);   // product of 8 dists <= (1.5e3)^8, fp32-safe
    }
    return s;
}

// diagonal-straddling tile: per-entry exponent 2 (j>i) / 1 (j==i) / 0 (j<i)
__device__ __forceinline__ float logsumStraddle(const f32x4 (&acc)[4][2],
                                                const f32x2 (&sa01)[4], const f32x2 (&sa23)[4],
                                                const float sb[2],
                                                int wr, int wc, int quad, int l15,
                                                int I0, int J0) {
    float s = 0.0f;
    #pragma unroll
    for (int ti = 0; ti < 4; ++ti) {
        #pragma unroll
        for (int tj = 0; tj < 2; ++tj) {
            const int j = J0 + wc * 32 + tj * 16 + l15;
            float pr = 1.0f;
            #pragma unroll
            for (int r = 0; r < 4; ++r) {
                const int i = I0 + wr * 64 + ti * 16 + quad * 4 + r;
                const float sav = (r < 2) ? ((r & 1) ? sa01[ti].y : sa01[ti].x)
                                          : ((r & 1) ? sa23[ti].y : sa23[ti].x);
                float d = fmaf(-2.0f, acc[ti][tj][r], sav + sb[tj]);
                d = fmaxf(d, 1.0f);
                const float t = (j > i) ? d : 1.0f;
                const float u = (j >= i) ? d : 1.0f;
                pr *= t * u;
            }
            s += __log2f(pr);
        }
    }
    return s;
}

__global__ __launch_bounds__(256) void mqjs_main(
    const unsigned char* __restrict__ x1q, const unsigned char* __restrict__ x2q,
    const unsigned char* __restrict__ pq,
    const float* __restrict__ sq1, const float* __restrict__ sq2,
    const float* __restrict__ sqp, float* __restrict__ partials) {

    // 48 KB LDS: 3-buffer B staging, depth-2 prefetch, counted-vmcnt pipeline.
    // Epilogue of tile jj-1 executes inside the MFMA region of tile jj
    // (two named acc sets) so VALU fills the MFMA issue shadow.
    __shared__ __align__(16) unsigned char Bs[3][2 * BJ * 128];
    __shared__ float red[4];

    const int tid = threadIdx.x;
    const int lane = tid & 63;
    const int wv = tid >> 6;
    const int wr = wv >> 1, wc = wv & 1;      // wave: 64 I-rows x 32 J-cols
    const int quad = lane >> 4, l15 = lane & 15;
    const int srow = lane >> 3;
    const int sblk = (lane & 7) ^ srow;

    const int z = blockIdx.z;
    const int I0 = blockIdx.y * BM;
    const int jbase = blockIdx.x * JG;
    const int pid = (z * GI + blockIdx.y) * GJ + blockIdx.x;
    const float wse = -(float)N / (float)(N - 1);

    int jj0 = 0;
    if (z == 2) {                              // first J-tile touching j >= i
        jj0 = 2 * (int)blockIdx.y - jbase;
        if (jj0 < 0) jj0 = 0;
        if (jj0 >= JG) { if (tid == 0) partials[pid] = 0.0f; return; }
    }

    const unsigned char* Ag = (z == 1) ? x2q : x1q;
    const unsigned char* Bg = (z == 2) ? x1q : pq;
    const float* sqAg = (z == 1) ? sq2 : sq1;
    const float* sqBg = (z == 2) ? sq1 : sqp;

    // A fragments + sqA straight from global (once per block; L2-resident)
    i32x8 af[2][4];
    f32x2 sa01[4], sa23[4];
    #pragma unroll
    for (int ti = 0; ti < 4; ++ti) {
        #pragma unroll
        for (int kc = 0; kc < 2; ++kc) {
            const size_t ro = (size_t)(I0 + wr * 64 + ti * 16 + l15) * D + kc * 128 + quad * 32;
            af[kc][ti] = *(const i32x8*)(Ag + ro);
        }
        const int sbase = I0 + wr * 64 + ti * 16 + quad * 4;
        sa01[ti] = (f32x2){sqAg[sbase], sqAg[sbase + 1]};
        sa23[ti] = (f32x2){sqAg[sbase + 2], sqAg[sbase + 3]};
    }

    // prologue: stage tiles jj0 -> buf0, jj0+1 -> buf1 (4 loads each per wave)
    stageB(Bg, Bs[0],        (jbase + jj0) * BJ, 0,   wv, srow, sblk);
    stageB(Bg, Bs[0] + 8192, (jbase + jj0) * BJ, 128, wv, srow, sblk);
    if (jj0 + 1 < JG) {
        stageB(Bg, Bs[1],        (jbase + jj0 + 1) * BJ, 0,   wv, srow, sblk);
        stageB(Bg, Bs[1] + 8192, (jbase + jj0 + 1) * BJ, 128, wv, srow, sblk);
    }

    float tsum = 0.0f;
    const f32x4 zero4 = {0.0f, 0.0f, 0.0f, 0.0f};

    // ---- pipeline stages as inlined lambdas ------------------------------
    // MFMA_TILE(jj): wait/barrier, load sb (first: oldest in VMEM FIFO),
    // stage jj+2, ds_read B-frags, 16 MFMAs into accC (C=0 on first rank).
    auto MFMA_TILE = [&](int jj, f32x4 (&accC)[4][2], float (&sbC)[2]) {
        if (jj + 1 < JG) asm volatile("s_waitcnt vmcnt(4)" ::: "memory");
        else             asm volatile("s_waitcnt vmcnt(0)" ::: "memory");
        asm volatile("s_barrier" ::: "memory");
        const int J0 = (jbase + jj) * BJ;
        sbC[0] = sqBg[J0 + wc * 32 + l15];          // issued before stage: FIFO-oldest
        sbC[1] = sqBg[J0 + wc * 32 + 16 + l15];
        if (jj + 2 < JG) {                          // depth-2 prefetch into freed buffer
            const int b2 = (jj + 2 - jj0) % 3;
            stageB(Bg, Bs[b2],        (jbase + jj + 2) * BJ, 0,   wv, srow, sblk);
            stageB(Bg, Bs[b2] + 8192, (jbase + jj + 2) * BJ, 128, wv, srow, sblk);
        }
        const int cur = (jj - jj0) % 3;
        i32x8 bfr0[2], bfr1[2];
        #pragma unroll
        for (int tj = 0; tj < 2; ++tj) {
            bfr0[tj] = read_frag(Bs[cur],        wc * 32 + tj * 16 + l15, quad);
            bfr1[tj] = read_frag(Bs[cur] + 8192, wc * 32 + tj * 16 + l15, quad);
        }
        #pragma unroll
        for (int ti = 0; ti < 4; ++ti)
            #pragma unroll
            for (int tj = 0; tj < 2; ++tj)
                accC[ti][tj] = mfma8(af[0][ti], bfr0[tj], zero4);   // C=0: no acc init
        #pragma unroll
        for (int ti = 0; ti < 4; ++ti)
            #pragma unroll
            for (int tj = 0; tj < 2; ++tj)
                accC[ti][tj] = mfma8(af[1][ti], bfr1[tj], accC[ti][tj]);
    };

    // EPI(jjPrev): pure-register VALU; scheduler interleaves into MFMA shadow.
    auto EPI = [&](int jjPrev, const f32x4 (&accP)[4][2], const float (&sbP)[2]) {
        const int J0p = (jbase + jjPrev) * BJ;
        if (z < 2) {
            tsum += 0.5f * logsumP(accP, sa01, sa23, sbP);
        } else if (J0p >= I0 + BM) {
            tsum += wse * logsumP(accP, sa01, sa23, sbP);  // upper full: weight 2*0.5*wse
        } else {
            tsum += 0.5f * wse * logsumStraddle(accP, sa01, sa23, sbP, wr, wc, quad, l15, I0, J0p);
        }
    };

    // ---- software-pipelined main loop ------------------------------------
    f32x4 accA[4][2], accB[4][2];
    float sbA[2], sbB[2];

    MFMA_TILE(jj0, accA, sbA);                    // fill stage, no epilogue yet
    for (int jj = jj0 + 1; jj < JG; ++jj) {
        if (((jj - jj0) & 1) == 1) {
            MFMA_TILE(jj, accB, sbB);
            EPI(jj - 1, accA, sbA);
        } else {
            MFMA_TILE(jj, accA, sbA);
            EPI(jj - 1, accB, sbB);
        }
    }
    if (((JG - jj0) & 1) == 1) EPI(JG - 1, accA, sbA);   // T odd -> last fill was accA
    else                       EPI(JG - 1, accB, sbB);

    tsum *= 0.6931471805599453f;   // log2 -> ln, applied once
    #pragma unroll
    for (int o = 32; o > 0; o >>= 1) tsum += __shfl_down(tsum, o, 64);
    if (lane == 0) red[wv] = tsum;
    __syncthreads();
    if (tid == 0) partials[pid] = red[0] + red[1] + red[2] + red[3];
}

// reduce 3072 partials (double accumulation) -> final scalar
__global__ void finalize_kernel(const float* __restrict__ partials, float* __restrict__ out) {
    const int tid = threadIdx.x;              // 768 threads
    const float4 v = ((const float4*)partials)[tid];
    double s = (double)v.x + (double)v.y + (double)v.z + (double)v.w;
    #pragma unroll
    for (int o = 32; o > 0; o >>= 1) s += __shfl_down(s, o, 64);
    __shared__ double r[12];
    if ((tid & 63) == 0) r[tid >> 6] = s;
    __syncthreads();
    if (tid == 0) {
        double t = 0.0;
        #pragma unroll
        for (int i = 0; i < 12; ++i) t += r[i];
        out[0] = (float)(t / (double)N);
    }
}

extern "C" void kernel_launch(void* const* d_in, const int* in_sizes, int n_in,
                              void* d_out, int out_size, void* d_ws, size_t ws_size,
                              hipStream_t stream) {
    const float* x1 = (const float*)d_in[0];
    const float* x2 = (const float*)d_in[1];

    char* ws = (char*)d_ws;
    const size_t MBYTES = (size_t)N * D;                  // 2 MiB per fp8 matrix
    unsigned* x1q = (unsigned*)(ws);
    unsigned* x2q = (unsigned*)(ws + MBYTES);
    unsigned* pq  = (unsigned*)(ws + 2 * MBYTES);
    float* sq1 = (float*)(ws + 3 * MBYTES);
    float* sq2 = (float*)(ws + 3 * MBYTES + (size_t)N * 4);
    float* sqp = (float*)(ws + 3 * MBYTES + (size_t)N * 8);
    float* partials = (float*)(ws + 3 * MBYTES + (size_t)N * 12);

    prep_kernel<<<N / 4, 256, 0, stream>>>(x1, x2, x1q, x2q, pq, sq1, sq2, sqp);
    mqjs_main<<<dim3(GJ, GI, 3), 256, 0, stream>>>(
        (const unsigned char*)x1q, (const unsigned char*)x2q, (const unsigned char*)pq,
        sq1, sq2, sqp, partials);
    finalize_kernel<<<1, 768, 0, stream>>>(partials, (float*)d_out);
}

// Round 4
// 139.458 us; speedup vs baseline: 1.3748x; 1.3748x over previous
//
#include <hip/hip_runtime.h>

#define N 8192
#define D 256
#define BM 128                    // I-tile rows
#define BJ 64                     // J-tile rows
#define JG 8                      // J-tiles per block
#define GJ (N / BJ / JG)          // 16
#define GI (N / BM)               // 64
#define NPART (3 * GI * GJ)       // 3072 partials

typedef int   i32x4 __attribute__((ext_vector_type(4)));
typedef int   i32x8 __attribute__((ext_vector_type(8)));
typedef float f32x4 __attribute__((ext_vector_type(4)));
typedef float f32x2 __attribute__((ext_vector_type(2)));

// -------- prep: fp32 -> fp8 e4m3 (packed), norms of the DEQUANTIZED values ----
__device__ __forceinline__ unsigned pack_fp8x4(float a, float b, float c, float d) {
    unsigned lo = __builtin_amdgcn_cvt_pk_fp8_f32(a, b, 0, false);
    return __builtin_amdgcn_cvt_pk_fp8_f32(c, d, lo, true);
}
__device__ __forceinline__ float dequant_sumsq(unsigned q) {
    const float v0 = __builtin_amdgcn_cvt_f32_fp8(q, 0);
    const float v1 = __builtin_amdgcn_cvt_f32_fp8(q, 1);
    const float v2 = __builtin_amdgcn_cvt_f32_fp8(q, 2);
    const float v3 = __builtin_amdgcn_cvt_f32_fp8(q, 3);
    return fmaf(v0, v0, fmaf(v1, v1, fmaf(v2, v2, v3 * v3)));
}

__global__ void prep_kernel(const float* __restrict__ x1, const float* __restrict__ x2,
                            unsigned* __restrict__ x1q, unsigned* __restrict__ x2q,
                            unsigned* __restrict__ pq,
                            float* __restrict__ sq1, float* __restrict__ sq2,
                            float* __restrict__ sqp) {
    const int tid = threadIdx.x, lane = tid & 63, wv = tid >> 6;
    const int row = blockIdx.x * 4 + wv;
    const size_t eb = (size_t)row * D + lane * 4;
    const float4 a = *(const float4*)(x1 + eb);
    const float4 b = *(const float4*)(x2 + eb);
    const float px = 0.5f * (a.x + b.x), py = 0.5f * (a.y + b.y);
    const float pz = 0.5f * (a.z + b.z), pw = 0.5f * (a.w + b.w);
    const unsigned qa = pack_fp8x4(a.x, a.y, a.z, a.w);
    const unsigned qb = pack_fp8x4(b.x, b.y, b.z, b.w);
    const unsigned qp = pack_fp8x4(px, py, pz, pw);
    const size_t wb = (size_t)row * (D / 4) + lane;
    x1q[wb] = qa; x2q[wb] = qb; pq[wb] = qp;
    float s1 = dequant_sumsq(qa), s2 = dequant_sumsq(qb), sp = dequant_sumsq(qp);
    #pragma unroll
    for (int o = 32; o > 0; o >>= 1) {
        s1 += __shfl_down(s1, o, 64);
        s2 += __shfl_down(s2, o, 64);
        sp += __shfl_down(sp, o, 64);
    }
    if (lane == 0) { sq1[row] = s1; sq2[row] = s2; sqp[row] = sp; }
}

// -------- main ---------------------------------------------------------------
__device__ __forceinline__ f32x4 mfma8(i32x8 a, i32x8 b, f32x4 c) {
    return __builtin_amdgcn_mfma_scale_f32_16x16x128_f8f6f4(
        a, b, c, 0, 0, 0, 0x7F7F7F7F, 0, 0x7F7F7F7F);
}

// B-fragment from LDS: 32 fp8 (k-chunk quad*32) of row m; 16B blocks XOR-swizzled by row&7
__device__ __forceinline__ i32x8 read_frag(const unsigned char* Ts, int m, int quad) {
    const int r7 = m & 7;
    const i32x4 lo = *(const i32x4*)(Ts + m * 128 + ((((2 * quad)     ^ r7)) << 4));
    const i32x4 hi = *(const i32x4*)(Ts + m * 128 + ((((2 * quad + 1) ^ r7)) << 4));
    i32x8 f;
    f[0] = lo[0]; f[1] = lo[1]; f[2] = lo[2]; f[3] = lo[3];
    f[4] = hi[0]; f[5] = hi[1]; f[6] = hi[2]; f[7] = hi[3];
    return f;
}

// stage a 64-row x 128B K-chunk (8 KB, 8 groups); 1 global_load_lds per wave (8 waves)
__device__ __forceinline__ void stageB8(const unsigned char* __restrict__ g,
                                        unsigned char* s, int rowbase, size_t kb,
                                        int wv, int srow, int sblk) {
    const int row = wv * 8 + srow;
    __builtin_amdgcn_global_load_lds(
        (const __attribute__((address_space(1))) void*)(g + (size_t)(rowbase + row) * D + kb + sblk * 16),
        (__attribute__((address_space(3))) void*)(s + wv * 1024), 16, 0, 0);
}

// packed-f32 log2-sum over 16 entries (2 ti x 2 tj x 4 regs); caller applies ln2
__device__ __forceinline__ float logsumP(const f32x4 (&acc)[2][2],
                                         const f32x2 (&sa01)[2], const f32x2 (&sa23)[2],
                                         const float sb[2]) {
    float s = 0.0f;
    #pragma unroll
    for (int ti = 0; ti < 2; ++ti) {
        f32x2 pr = {1.0f, 1.0f};
        #pragma unroll
        for (int tj = 0; tj < 2; ++tj) {
            const f32x2 sbv = {sb[tj], sb[tj]};
            const f32x2 t01 = sa01[ti] + sbv, t23 = sa23[ti] + sbv;
            const f32x2 v01 = {acc[ti][tj][0], acc[ti][tj][1]};
            const f32x2 v23 = {acc[ti][tj][2], acc[ti][tj][3]};
            f32x2 d01 = t01 - 2.0f * v01;
            f32x2 d23 = t23 - 2.0f * v23;
            d01 = __builtin_elementwise_max(d01, (f32x2){1.0f, 1.0f});
            d23 = __builtin_elementwise_max(d23, (f32x2){1.0f, 1.0f});
            pr *= d01; pr *= d23;
        }
        s += __log2f(pr.x * pr.y);   // product of 8 dists <= (1.5e3)^8, fp32-safe
    }
    return s;
}

// diagonal-straddling tile: per-entry exponent 2 (j>i) / 1 (j==i) / 0 (j<i)
__device__ __forceinline__ float logsumStraddle(const f32x4 (&acc)[2][2],
                                                const f32x2 (&sa01)[2], const f32x2 (&sa23)[2],
                                                const float sb[2],
                                                int wr, int wc, int quad, int l15,
                                                int I0, int J0) {
    float s = 0.0f;
    #pragma unroll
    for (int ti = 0; ti < 2; ++ti) {
        #pragma unroll
        for (int tj = 0; tj < 2; ++tj) {
            const int j = J0 + wc * 32 + tj * 16 + l15;
            float pr = 1.0f;
            #pragma unroll
            for (int r = 0; r < 4; ++r) {
                const int i = I0 + wr * 32 + ti * 16 + quad * 4 + r;
                const float sav = (r < 2) ? ((r & 1) ? sa01[ti].y : sa01[ti].x)
                                          : ((r & 1) ? sa23[ti].y : sa23[ti].x);
                float d = fmaf(-2.0f, acc[ti][tj][r], sav + sb[tj]);
                d = fmaxf(d, 1.0f);
                const float t = (j > i) ? d : 1.0f;
                const float u = (j >= i) ? d : 1.0f;
                pr *= t * u;
            }
            s += __log2f(pr);
        }
    }
    return s;
}

__global__ __launch_bounds__(512, 4) void mqjs_main(
    const unsigned char* __restrict__ x1q, const unsigned char* __restrict__ x2q,
    const unsigned char* __restrict__ pq,
    const float* __restrict__ sq1, const float* __restrict__ sq2,
    const float* __restrict__ sqp, float* __restrict__ partials) {

    // 8 waves per block (2 waves/SIMD per block): wave = 32 I-rows x 32 J-cols.
    // 48 KB LDS: 3-buffer B staging, depth-2 prefetch, counted-vmcnt pipeline.
    __shared__ __align__(16) unsigned char Bs[3][2 * BJ * 128];
    __shared__ float red[8];

    const int tid = threadIdx.x;
    const int lane = tid & 63;
    const int wv = tid >> 6;                  // 0..7
    const int wr = wv >> 1, wc = wv & 1;      // wr: 32-row I-group, wc: 32-col J-group
    const int quad = lane >> 4, l15 = lane & 15;
    const int srow = lane >> 3;
    const int sblk = (lane & 7) ^ srow;

    const int z = blockIdx.z;
    const int I0 = blockIdx.y * BM;
    const int jbase = blockIdx.x * JG;
    const int pid = (z * GI + blockIdx.y) * GJ + blockIdx.x;
    const float wse = -(float)N / (float)(N - 1);

    int jj0 = 0;
    if (z == 2) {                              // first J-tile touching j >= i
        jj0 = 2 * (int)blockIdx.y - jbase;
        if (jj0 < 0) jj0 = 0;
        if (jj0 >= JG) { if (tid == 0) partials[pid] = 0.0f; return; }
    }

    const unsigned char* Ag = (z == 1) ? x2q : x1q;
    const unsigned char* Bg = (z == 2) ? x1q : pq;
    const float* sqAg = (z == 1) ? sq2 : sq1;
    const float* sqBg = (z == 2) ? sq1 : sqp;

    // A fragments + sqA straight from global (once per block; L2-resident)
    i32x8 af[2][2];                            // [kc][ti]
    f32x2 sa01[2], sa23[2];
    #pragma unroll
    for (int ti = 0; ti < 2; ++ti) {
        #pragma unroll
        for (int kc = 0; kc < 2; ++kc) {
            const size_t ro = (size_t)(I0 + wr * 32 + ti * 16 + l15) * D + kc * 128 + quad * 32;
            af[kc][ti] = *(const i32x8*)(Ag + ro);
        }
        const int sbase = I0 + wr * 32 + ti * 16 + quad * 4;
        const float4 sv = *(const float4*)(sqAg + sbase);   // 16B-aligned
        sa01[ti] = (f32x2){sv.x, sv.y};
        sa23[ti] = (f32x2){sv.z, sv.w};
    }

    // prologue: stage tiles jj0 -> buf0, jj0+1 -> buf1 (2 loads each per wave)
    stageB8(Bg, Bs[0],        (jbase + jj0) * BJ, 0,   wv, srow, sblk);
    stageB8(Bg, Bs[0] + 8192, (jbase + jj0) * BJ, 128, wv, srow, sblk);
    if (jj0 + 1 < JG) {
        stageB8(Bg, Bs[1],        (jbase + jj0 + 1) * BJ, 0,   wv, srow, sblk);
        stageB8(Bg, Bs[1] + 8192, (jbase + jj0 + 1) * BJ, 128, wv, srow, sblk);
    }

    float tsum = 0.0f;
    const f32x4 zero4 = {0.0f, 0.0f, 0.0f, 0.0f};
    int cur = 0;

    for (int jj = jj0; jj < JG; ++jj) {
        const int J0 = (jbase + jj) * BJ;

        // wait for stage(jj) (2 per-wave loads); leave stage(jj+1) in flight.
        // Barrier also proves all waves finished reading the buffer restaged below.
        if (jj + 1 < JG) asm volatile("s_waitcnt vmcnt(2)" ::: "memory");
        else             asm volatile("s_waitcnt vmcnt(0)" ::: "memory");
        asm volatile("s_barrier" ::: "memory");

        // sb FIRST (oldest in this iter's VMEM FIFO): the epilogue's sb-wait then
        // drains old stages but leaves the jj+2 prefetch below in flight.
        float sb[2];
        sb[0] = sqBg[J0 + wc * 32 + l15];
        sb[1] = sqBg[J0 + wc * 32 + 16 + l15];

        if (jj + 2 < JG) {                     // depth-2 prefetch into freed buffer
            const int b2 = (cur == 0) ? 2 : cur - 1;
            stageB8(Bg, Bs[b2],        (jbase + jj + 2) * BJ, 0,   wv, srow, sblk);
            stageB8(Bg, Bs[b2] + 8192, (jbase + jj + 2) * BJ, 128, wv, srow, sblk);
        }

        i32x8 bfr0[2], bfr1[2];
        #pragma unroll
        for (int tj = 0; tj < 2; ++tj) {
            bfr0[tj] = read_frag(Bs[cur],        wc * 32 + tj * 16 + l15, quad);
            bfr1[tj] = read_frag(Bs[cur] + 8192, wc * 32 + tj * 16 + l15, quad);
        }

        f32x4 acc[2][2];
        __builtin_amdgcn_s_setprio(1);
        #pragma unroll
        for (int ti = 0; ti < 2; ++ti)
            #pragma unroll
            for (int tj = 0; tj < 2; ++tj)
                acc[ti][tj] = mfma8(af[0][ti], bfr0[tj], zero4);   // C=0: no acc init
        #pragma unroll
        for (int ti = 0; ti < 2; ++ti)
            #pragma unroll
            for (int tj = 0; tj < 2; ++tj)
                acc[ti][tj] = mfma8(af[1][ti], bfr1[tj], acc[ti][tj]);
        __builtin_amdgcn_s_setprio(0);

        if (z < 2) {
            tsum += 0.5f * logsumP(acc, sa01, sa23, sb);
        } else if (J0 >= I0 + BM) {
            tsum += wse * logsumP(acc, sa01, sa23, sb);          // upper full: weight 2*0.5*wse
        } else {
            tsum += 0.5f * wse * logsumStraddle(acc, sa01, sa23, sb, wr, wc, quad, l15, I0, J0);
        }

        cur = (cur == 2) ? 0 : cur + 1;
    }

    tsum *= 0.6931471805599453f;   // log2 -> ln, applied once
    #pragma unroll
    for (int o = 32; o > 0; o >>= 1) tsum += __shfl_down(tsum, o, 64);
    if (lane == 0) red[wv] = tsum;
    __syncthreads();
    if (tid == 0) {
        float t = 0.0f;
        #pragma unroll
        for (int i = 0; i < 8; ++i) t += red[i];
        partials[pid] = t;
    }
}

// reduce 3072 partials (double accumulation) -> final scalar
__global__ void finalize_kernel(const float* __restrict__ partials, float* __restrict__ out) {
    const int tid = threadIdx.x;              // 768 threads
    const float4 v = ((const float4*)partials)[tid];
    double s = (double)v.x + (double)v.y + (double)v.z + (double)v.w;
    #pragma unroll
    for (int o = 32; o > 0; o >>= 1) s += __shfl_down(s, o, 64);
    __shared__ double r[12];
    if ((tid & 63) == 0) r[tid >> 6] = s;
    __syncthreads();
    if (tid == 0) {
        double t = 0.0;
        #pragma unroll
        for (int i = 0; i < 12; ++i) t += r[i];
        out[0] = (float)(t / (double)N);
    }
}

extern "C" void kernel_launch(void* const* d_in, const int* in_sizes, int n_in,
                              void* d_out, int out_size, void* d_ws, size_t ws_size,
                              hipStream_t stream) {
    const float* x1 = (const float*)d_in[0];
    const float* x2 = (const float*)d_in[1];

    char* ws = (char*)d_ws;
    const size_t MBYTES = (size_t)N * D;                  // 2 MiB per fp8 matrix
    unsigned* x1q = (unsigned*)(ws);
    unsigned* x2q = (unsigned*)(ws + MBYTES);
    unsigned* pq  = (unsigned*)(ws + 2 * MBYTES);
    float* sq1 = (float*)(ws + 3 * MBYTES);
    float* sq2 = (float*)(ws + 3 * MBYTES + (size_t)N * 4);
    float* sqp = (float*)(ws + 3 * MBYTES + (size_t)N * 8);
    float* partials = (float*)(ws + 3 * MBYTES + (size_t)N * 12);

    prep_kernel<<<N / 4, 256, 0, stream>>>(x1, x2, x1q, x2q, pq, sq1, sq2, sqp);
    mqjs_main<<<dim3(GJ, GI, 3), 512, 0, stream>>>(
        (const unsigned char*)x1q, (const unsigned char*)x2q, (const unsigned char*)pq,
        sq1, sq2, sqp, partials);
    finalize_kernel<<<1, 768, 0, stream>>>(partials, (float*)d_out);
}